// Round 9
// baseline (254.505 us; speedup 1.0000x reference)
//
#include <hip/hip_runtime.h>

typedef __attribute__((ext_vector_type(8))) short bf16x8;
typedef __attribute__((ext_vector_type(4))) float f32x4;
typedef __attribute__((ext_vector_type(8))) unsigned short u16x8;
typedef __attribute__((ext_vector_type(4))) unsigned short u16x4;

#define S_LEN 2048
#define BATCH 2
#define EMB 1024
#define NH 16
#define HDIM 64
#define M_ROWS (S_LEN * BATCH)   // 4096
#define N_QKV (3 * EMB)          // 3072

typedef const __attribute__((address_space(1))) unsigned int* gptr_t;
typedef __attribute__((address_space(3))) unsigned int* lptr_t;

__device__ __forceinline__ unsigned short f2b(float f) {
  union { float f; unsigned u; } v; v.f = f;
  unsigned r = v.u + 0x7fff + ((v.u >> 16) & 1);
  return (unsigned short)(r >> 16);
}
// round-half-up: shorter dep chain; fine for P in [0,1]
__device__ __forceinline__ unsigned short f2b_fast(float f) {
  union { float f; unsigned u; } v; v.f = f;
  return (unsigned short)((v.u + 0x8000u) >> 16);
}
__device__ __forceinline__ float b2f(unsigned short s) {
  union { float f; unsigned u; } v; v.u = ((unsigned)s) << 16;
  return v.f;
}

// ---------------- fp32 -> bf16 conversion (memory-bound) ----------------
__global__ __launch_bounds__(256) void cvt_f32_bf16(const float* __restrict__ in,
                                                    unsigned short* __restrict__ out,
                                                    int n4) {
  int i = blockIdx.x * 256 + threadIdx.x;
  if (i >= n4) return;
  float4 a = reinterpret_cast<const float4*>(in)[i];
  u16x4 o;
  o[0] = f2b(a.x); o[1] = f2b(a.y); o[2] = f2b(a.z); o[3] = f2b(a.w);
  reinterpret_cast<u16x4*>(out)[i] = o;
}

// ---------------- bf16 GEMM, C = A(M,K) * B(N,K)^T ----------------
// 128x128 tile, BK=32, 4 waves (2x2), each wave 64x64 out (4x4 frags of 16x16)
// Staging: global_load_lds width=16, linear LDS (m97 structure)
template <int OUT_BF16>
__global__ __launch_bounds__(256) void gemm_bt(const unsigned short* __restrict__ A,
                                               const unsigned short* __restrict__ Bm,
                                               void* __restrict__ Cv,
                                               int Md, int Nd, int Kd) {
  __shared__ unsigned short As[128][32];  // linear: global_load_lds needs contiguous dest
  __shared__ unsigned short Bs[128][32];
  int t = threadIdx.x;
  int bm = blockIdx.y, bn = blockIdx.x;
  int wid = t >> 6, lane = t & 63;
  int wr = wid >> 1, wc = wid & 1;
  int fr = lane & 15, fq = lane >> 4;
  int lrow = lane >> 2;          // 0..15: row within 16-row chunk
  int lcol = (lane & 3) * 8;     // element col within 32 (16B granules)

  f32x4 acc[4][4];
#pragma unroll
  for (int i = 0; i < 4; ++i)
#pragma unroll
    for (int j = 0; j < 4; ++j) acc[i][j] = (f32x4){0.f, 0.f, 0.f, 0.f};

  int nkt = Kd >> 5;
  for (int kt = 0; kt < nkt; ++kt) {
    // each wave stages 32 rows of A and 32 rows of B (2 chunks of 16 rows each)
    const unsigned short* ga = A + (size_t)(bm * 128 + wid * 32 + lrow) * Kd + kt * 32 + lcol;
    const unsigned short* gb = Bm + (size_t)(bn * 128 + wid * 32 + lrow) * Kd + kt * 32 + lcol;
#pragma unroll
    for (int j = 0; j < 2; ++j) {
      __builtin_amdgcn_global_load_lds((gptr_t)(ga + (size_t)j * 16 * Kd),
                                       (lptr_t)&As[wid * 32 + j * 16][0], 16, 0, 0);
      __builtin_amdgcn_global_load_lds((gptr_t)(gb + (size_t)j * 16 * Kd),
                                       (lptr_t)&Bs[wid * 32 + j * 16][0], 16, 0, 0);
    }
    __syncthreads();   // drains vmcnt -> LDS tiles complete

    bf16x8 af[4], bfv[4];
#pragma unroll
    for (int mt = 0; mt < 4; ++mt)
      af[mt] = *reinterpret_cast<const bf16x8*>(&As[wr * 64 + mt * 16 + fr][fq * 8]);
#pragma unroll
    for (int nt = 0; nt < 4; ++nt)
      bfv[nt] = *reinterpret_cast<const bf16x8*>(&Bs[wc * 64 + nt * 16 + fr][fq * 8]);
#pragma unroll
    for (int mt = 0; mt < 4; ++mt)
#pragma unroll
      for (int nt = 0; nt < 4; ++nt)
        acc[mt][nt] = __builtin_amdgcn_mfma_f32_16x16x32_bf16(af[mt], bfv[nt], acc[mt][nt], 0, 0, 0);
    __syncthreads();
  }

#pragma unroll
  for (int mt = 0; mt < 4; ++mt)
#pragma unroll
    for (int nt = 0; nt < 4; ++nt)
#pragma unroll
      for (int r = 0; r < 4; ++r) {
        int row = bm * 128 + wr * 64 + mt * 16 + fq * 4 + r;
        int col = bn * 128 + wc * 64 + nt * 16 + fr;
        float val = acc[mt][nt][r];
        if (OUT_BF16)
          reinterpret_cast<unsigned short*>(Cv)[(size_t)row * Nd + col] = f2b(val);
        else
          reinterpret_cast<float*>(Cv)[(size_t)row * Nd + col] = val;
      }
}

// ---------------- V transpose: qkv -> Vt[b*16+h][d][s] ----------------
// grid (S/64, B*H). LDS tile [64][72] with chunk-XOR swizzle -> 2-way banks.
__global__ __launch_bounds__(256) void vtrans(const unsigned short* __restrict__ qkv,
                                              unsigned short* __restrict__ vt) {
  __shared__ unsigned short Ts[64][72];
  int t = threadIdx.x;
  int kb = blockIdx.x;
  int bh = blockIdx.y;
  int b = bh >> 4, h = bh & 15;
  int k0 = kb * 64;
#pragma unroll
  for (int i = 0; i < 2; ++i) {
    int c = t + i * 256;
    int r = c >> 3, q = c & 7;                 // V row k0+r, d-chunk q
    int chunk = q ^ ((r >> 3) & 7);            // XOR swizzle (read side matches)
    *reinterpret_cast<u16x8*>(&Ts[r][chunk * 8]) =
        *reinterpret_cast<const u16x8*>(
            qkv + ((size_t)(k0 + r) * BATCH + b) * N_QKV + h * 192 + 128 + q * 8);
  }
  __syncthreads();
#pragma unroll
  for (int i = 0; i < 2; ++i) {
    int c = t + i * 256;
    int d = c >> 3, q = c & 7;                 // output row d, k-chunk q
    u16x8 o;
#pragma unroll
    for (int j = 0; j < 8; ++j) {
      int k = q * 8 + j;
      int chunk = (d >> 3) ^ q;                // (k>>3)&7 == q
      o[j] = Ts[k][chunk * 8 + (d & 7)];
    }
    *reinterpret_cast<u16x8*>(&vt[((size_t)bh * 64 + d) * S_LEN + k0 + q * 8]) = o;
  }
}

// ---------------- flash attention (swapped-operand, in-register softmax) ----
// grid: (S/64, B*H); 4 waves x 16 q-rows. KV tiles of 64. dbuf K/Vt LDS.
// This round: cvt_pk P-pack (T12 primitive), defer-max (T13, thr=8),
// max3-fusable max tree (T17). Layout/transport unchanged from r8-verified.
__global__ __launch_bounds__(256) void attn_kernel(const unsigned short* __restrict__ qkv,
                                                   const unsigned short* __restrict__ vt,
                                                   unsigned short* __restrict__ att) {
  __shared__ unsigned short Ks[2][64][72];   // [k][d], dbuf
  __shared__ unsigned short VtS[2][64][72];  // [d][k], dbuf
  int t = threadIdx.x;
  int wid = t >> 6, lane = t & 63;
  int fr = lane & 15, fq = lane >> 4;
  int bh = blockIdx.y;
  int b = bh >> 4;   // H = 16
  int h = bh & 15;
  int q0 = blockIdx.x * 64;

  int srow = t >> 3, sc8 = (t & 7) * 8;      // staging row/col (chunk1: row+32)

  // Q fragments (B operand): lane holds q-row fr, d = c*32 + fq*8 + j
  int qi = q0 + wid * 16 + fr;
  const unsigned short* qrow = qkv + ((size_t)qi * BATCH + b) * N_QKV + h * 192;
  bf16x8 qf[2];
  qf[0] = *reinterpret_cast<const bf16x8*>(qrow + fq * 8);
  qf[1] = *reinterpret_cast<const bf16x8*>(qrow + 32 + fq * 8);
  // pre-scale Q by 1/sqrt(64) = 0.125 (power of 2: exact in bf16)
#pragma unroll
  for (int c = 0; c < 2; ++c)
#pragma unroll
    for (int j = 0; j < 8; ++j)
      qf[c][j] = (short)f2b_fast(0.125f * b2f((unsigned short)qf[c][j]));

  // O^T accumulator: lane holds q=fr, d = dt*16 + fq*4 + r
  f32x4 o[4];
#pragma unroll
  for (int dt = 0; dt < 4; ++dt) o[dt] = (f32x4){0.f, 0.f, 0.f, 0.f};
  float m_run = -1e30f, l_run = 0.f;

  // redistribution constants
  int srcA = fr + ((fq & 1) << 5);   // fr + 32*(fq&1)
  int srcB = srcA + 16;
  int hi = (fq >> 1) & 1;

  // prologue: stage tile 0 into buf 0
#pragma unroll
  for (int i = 0; i < 2; ++i) {
    int row = srow + i * 32;
    *reinterpret_cast<u16x8*>(&Ks[0][row][sc8]) = *reinterpret_cast<const u16x8*>(
        qkv + ((size_t)row * BATCH + b) * N_QKV + h * 192 + 64 + sc8);
    *reinterpret_cast<u16x8*>(&VtS[0][row][sc8]) = *reinterpret_cast<const u16x8*>(
        vt + ((size_t)bh * 64 + row) * S_LEN + sc8);
  }
  __syncthreads();

  for (int kt = 0; kt < S_LEN / 64; ++kt) {
    int cur = kt & 1, nxt = cur ^ 1;

    // T14: issue next tile's global loads first; complete under compute
    u16x8 kreg[2], vreg[2];
    if (kt + 1 < S_LEN / 64) {
#pragma unroll
      for (int i = 0; i < 2; ++i) {
        int row = srow + i * 32;
        kreg[i] = *reinterpret_cast<const u16x8*>(
            qkv + ((size_t)((kt + 1) * 64 + row) * BATCH + b) * N_QKV + h * 192 + 64 + sc8);
        vreg[i] = *reinterpret_cast<const u16x8*>(
            vt + ((size_t)bh * 64 + row) * S_LEN + (kt + 1) * 64 + sc8);
      }
    }

    // S^T = K * Q^T : mfma(A=K rows, B=Q rows). Lane: q=fr, k=nt*16+fq*4+r
    f32x4 snt[4];
#pragma unroll
    for (int nt = 0; nt < 4; ++nt) {
      bf16x8 bk0 = *reinterpret_cast<const bf16x8*>(&Ks[cur][nt * 16 + fr][fq * 8]);
      bf16x8 bk1 = *reinterpret_cast<const bf16x8*>(&Ks[cur][nt * 16 + fr][32 + fq * 8]);
      f32x4 s = (f32x4){0.f, 0.f, 0.f, 0.f};
      s = __builtin_amdgcn_mfma_f32_16x16x32_bf16(bk0, qf[0], s, 0, 0, 0);
      s = __builtin_amdgcn_mfma_f32_16x16x32_bf16(bk1, qf[1], s, 0, 0, 0);
      snt[nt] = s;
    }

    // row max: max3-fusable chains (clang fuses fmaxf(fmaxf(a,b),c) -> v_max3)
    float ma = fmaxf(fmaxf(snt[0][0], snt[0][1]), snt[0][2]);
    ma = fmaxf(fmaxf(ma, snt[0][3]), snt[1][0]);
    ma = fmaxf(fmaxf(ma, snt[1][1]), snt[1][2]);
    float mb = fmaxf(fmaxf(snt[2][0], snt[2][1]), snt[2][2]);
    mb = fmaxf(fmaxf(mb, snt[2][3]), snt[3][0]);
    mb = fmaxf(fmaxf(mb, snt[3][1]), snt[3][2]);
    float mx = fmaxf(fmaxf(ma, snt[1][3]), fmaxf(mb, snt[3][3]));
    mx = fmaxf(mx, __shfl_xor(mx, 16));
    mx = fmaxf(mx, __shfl_xor(mx, 32));

    // T13 defer-max: only rescale when some row grew by > 8
    if (!__all(mx - m_run <= 8.0f)) {
      float mnew = fmaxf(m_run, mx);
      float alpha = __expf(m_run - mnew);
      m_run = mnew;
      l_run *= alpha;
#pragma unroll
      for (int dt = 0; dt < 4; ++dt) o[dt] *= alpha;
    }

    // P = exp(S - m_run)  (bounded by e^8 under defer-max)
    float rs = 0.f;
#pragma unroll
    for (int nt = 0; nt < 4; ++nt)
#pragma unroll
      for (int r = 0; r < 4; ++r) {
        float pv = __expf(snt[nt][r] - m_run);
        snt[nt][r] = pv;
        rs += pv;
      }
    rs += __shfl_xor(rs, 16);
    rs += __shfl_xor(rs, 32);
    l_run += rs;

    // pack P to bf16 dwords via v_cvt_pk_bf16_f32 (1 inst per dword, RNE)
    unsigned pd[8];
#pragma unroll
    for (int nt = 0; nt < 4; ++nt)
#pragma unroll
      for (int hh = 0; hh < 2; ++hh)
        asm("v_cvt_pk_bf16_f32 %0, %1, %2"
            : "=v"(pd[nt * 2 + hh])
            : "v"(snt[nt][2 * hh]), "v"(snt[nt][2 * hh + 1]));

    // redistribute to B-operand layout and do PV:
    // dest dword dwi of kc needs src lane (fr+32*(fq&1)+16*(dwi>>1)),
    // src dword 4kc + 2*(fq>>1) + (dwi&1)   [r8-verified mapping]
#pragma unroll
    for (int kc = 0; kc < 2; ++kc) {
      int base = kc * 4;
      unsigned a0 = (unsigned)__shfl((int)pd[base + 0], srcA);
      unsigned a1 = (unsigned)__shfl((int)pd[base + 1], srcA);
      unsigned a2 = (unsigned)__shfl((int)pd[base + 2], srcA);
      unsigned a3 = (unsigned)__shfl((int)pd[base + 3], srcA);
      unsigned c0 = (unsigned)__shfl((int)pd[base + 0], srcB);
      unsigned c1 = (unsigned)__shfl((int)pd[base + 1], srcB);
      unsigned c2 = (unsigned)__shfl((int)pd[base + 2], srcB);
      unsigned c3 = (unsigned)__shfl((int)pd[base + 3], srcB);
      union { unsigned u[4]; bf16x8 v; } pb;
      pb.u[0] = hi ? a2 : a0;
      pb.u[1] = hi ? a3 : a1;
      pb.u[2] = hi ? c2 : c0;
      pb.u[3] = hi ? c3 : c1;
#pragma unroll
      for (int dt = 0; dt < 4; ++dt) {
        bf16x8 vb = *reinterpret_cast<const bf16x8*>(&VtS[cur][dt * 16 + fr][kc * 32 + fq * 8]);
        o[dt] = __builtin_amdgcn_mfma_f32_16x16x32_bf16(vb, pb.v, o[dt], 0, 0, 0);
      }
    }

    // write next tile to the other buffer
    if (kt + 1 < S_LEN / 64) {
#pragma unroll
      for (int i = 0; i < 2; ++i) {
        int row = srow + i * 32;
        *reinterpret_cast<u16x8*>(&Ks[nxt][row][sc8]) = kreg[i];
        *reinterpret_cast<u16x8*>(&VtS[nxt][row][sc8]) = vreg[i];
      }
    }
    __syncthreads();   // single barrier per tile
  }

  // epilogue: O^T lane layout q=fr, d = dt*16+fq*4+r (r contiguous -> u16x4)
  float invl = 1.0f / l_run;
  int q = q0 + wid * 16 + fr;
#pragma unroll
  for (int dt = 0; dt < 4; ++dt) {
    u16x4 ov;
#pragma unroll
    for (int r = 0; r < 4; ++r) ov[r] = f2b(o[dt][r] * invl);
    int d = dt * 16 + fq * 4;
    *reinterpret_cast<u16x4*>(&att[((size_t)q * BATCH + b) * EMB + h * 64 + d]) = ov;
  }
}

extern "C" void kernel_launch(void* const* d_in, const int* in_sizes, int n_in,
                              void* d_out, int out_size, void* d_ws, size_t ws_size,
                              hipStream_t stream) {
  const float* q_in  = (const float*)d_in[0];
  const float* w_in  = (const float*)d_in[3];
  const float* w_out = (const float*)d_in[4];
  float* out = (float*)d_out;

  unsigned short* ws  = (unsigned short*)d_ws;
  unsigned short* Xb  = ws;                                  // 4096x1024 (dead after gemm1)
  unsigned short* Wb  = Xb + (size_t)M_ROWS * EMB;           // 3072x1024
  unsigned short* Ob  = Wb + (size_t)N_QKV * EMB;            // 1024x1024
  unsigned short* QKV = Ob + (size_t)EMB * EMB;              // 4096x3072
  unsigned short* ATT = QKV + (size_t)M_ROWS * N_QKV;        // 4096x1024
  unsigned short* Vt  = Xb;                                  // alias: 32*64*2048 == 4096*1024

  cvt_f32_bf16<<<(M_ROWS * EMB / 4 + 255) / 256, 256, 0, stream>>>(q_in, Xb, M_ROWS * EMB / 4);
  cvt_f32_bf16<<<(N_QKV * EMB / 4 + 255) / 256, 256, 0, stream>>>(w_in, Wb, N_QKV * EMB / 4);
  cvt_f32_bf16<<<(EMB * EMB / 4 + 255) / 256, 256, 0, stream>>>(w_out, Ob, EMB * EMB / 4);

  gemm_bt<1><<<dim3(N_QKV / 128, M_ROWS / 128), 256, 0, stream>>>(Xb, Wb, QKV, M_ROWS, N_QKV, EMB);
  vtrans<<<dim3(S_LEN / 64, BATCH * NH), 256, 0, stream>>>(QKV, Vt);
  attn_kernel<<<dim3(S_LEN / 64, BATCH * NH), 256, 0, stream>>>(QKV, Vt, ATT);
  gemm_bt<0><<<dim3(EMB / 128, M_ROWS / 128), 256, 0, stream>>>(ATT, Ob, out, M_ROWS, EMB, EMB);
}

// Round 10
// 238.027 us; speedup vs baseline: 1.0692x; 1.0692x over previous
//
#include <hip/hip_runtime.h>

typedef __attribute__((ext_vector_type(8))) short bf16x8;
typedef __attribute__((ext_vector_type(4))) float f32x4;
typedef __attribute__((ext_vector_type(8))) unsigned short u16x8;
typedef __attribute__((ext_vector_type(4))) unsigned short u16x4;

#define S_LEN 2048
#define BATCH 2
#define EMB 1024
#define NH 16
#define HDIM 64
#define M_ROWS (S_LEN * BATCH)   // 4096
#define N_QKV (3 * EMB)          // 3072

typedef const __attribute__((address_space(1))) unsigned int* gptr_t;
typedef __attribute__((address_space(3))) unsigned int* lptr_t;

__device__ __forceinline__ unsigned short f2b(float f) {
  union { float f; unsigned u; } v; v.f = f;
  unsigned r = v.u + 0x7fff + ((v.u >> 16) & 1);
  return (unsigned short)(r >> 16);
}
__device__ __forceinline__ unsigned short f2b_fast(float f) {
  union { float f; unsigned u; } v; v.f = f;
  return (unsigned short)((v.u + 0x8000u) >> 16);
}
__device__ __forceinline__ float b2f(unsigned short s) {
  union { float f; unsigned u; } v; v.u = ((unsigned)s) << 16;
  return v.f;
}

// ---------------- fp32 -> bf16 conversion (memory-bound) ----------------
__global__ __launch_bounds__(256) void cvt_f32_bf16(const float* __restrict__ in,
                                                    unsigned short* __restrict__ out,
                                                    int n4) {
  int i = blockIdx.x * 256 + threadIdx.x;
  if (i >= n4) return;
  float4 a = reinterpret_cast<const float4*>(in)[i];
  u16x4 o;
  o[0] = f2b(a.x); o[1] = f2b(a.y); o[2] = f2b(a.z); o[3] = f2b(a.w);
  reinterpret_cast<u16x4*>(out)[i] = o;
}

// ---------------- bf16 GEMM, C = A(M,K) * B(N,K)^T ----------------
// 128x128 tile, BK=64 as two [128][32] sub-buffers (m97 banking preserved),
// one barrier pair per 64-K: halves barrier-drain count vs BK=32.
template <int OUT_BF16>
__global__ __launch_bounds__(256) void gemm_bt(const unsigned short* __restrict__ A,
                                               const unsigned short* __restrict__ Bm,
                                               void* __restrict__ Cv,
                                               int Md, int Nd, int Kd) {
  __shared__ unsigned short As[2][128][32];
  __shared__ unsigned short Bs[2][128][32];
  int t = threadIdx.x;
  int bm = blockIdx.y, bn = blockIdx.x;
  int wid = t >> 6, lane = t & 63;
  int wr = wid >> 1, wc = wid & 1;
  int fr = lane & 15, fq = lane >> 4;
  int lrow = lane >> 2;          // 0..15: row within 16-row chunk
  int lcol = (lane & 3) * 8;     // element col within 32 (16B granules)

  f32x4 acc[4][4];
#pragma unroll
  for (int i = 0; i < 4; ++i)
#pragma unroll
    for (int j = 0; j < 4; ++j) acc[i][j] = (f32x4){0.f, 0.f, 0.f, 0.f};

  int nkt = Kd >> 6;
  for (int kt = 0; kt < nkt; ++kt) {
#pragma unroll
    for (int hf = 0; hf < 2; ++hf) {
      const unsigned short* ga =
          A + (size_t)(bm * 128 + wid * 32 + lrow) * Kd + kt * 64 + hf * 32 + lcol;
      const unsigned short* gb =
          Bm + (size_t)(bn * 128 + wid * 32 + lrow) * Kd + kt * 64 + hf * 32 + lcol;
#pragma unroll
      for (int j = 0; j < 2; ++j) {
        __builtin_amdgcn_global_load_lds((gptr_t)(ga + (size_t)j * 16 * Kd),
                                         (lptr_t)&As[hf][wid * 32 + j * 16][0], 16, 0, 0);
        __builtin_amdgcn_global_load_lds((gptr_t)(gb + (size_t)j * 16 * Kd),
                                         (lptr_t)&Bs[hf][wid * 32 + j * 16][0], 16, 0, 0);
      }
    }
    __syncthreads();   // drains vmcnt -> both halves complete

#pragma unroll
    for (int hf = 0; hf < 2; ++hf) {
      bf16x8 af[4], bfv[4];
#pragma unroll
      for (int mt = 0; mt < 4; ++mt)
        af[mt] = *reinterpret_cast<const bf16x8*>(&As[hf][wr * 64 + mt * 16 + fr][fq * 8]);
#pragma unroll
      for (int nt = 0; nt < 4; ++nt)
        bfv[nt] = *reinterpret_cast<const bf16x8*>(&Bs[hf][wc * 64 + nt * 16 + fr][fq * 8]);
#pragma unroll
      for (int mt = 0; mt < 4; ++mt)
#pragma unroll
        for (int nt = 0; nt < 4; ++nt)
          acc[mt][nt] = __builtin_amdgcn_mfma_f32_16x16x32_bf16(af[mt], bfv[nt], acc[mt][nt], 0, 0, 0);
    }
    __syncthreads();
  }

#pragma unroll
  for (int mt = 0; mt < 4; ++mt)
#pragma unroll
    for (int nt = 0; nt < 4; ++nt)
#pragma unroll
      for (int r = 0; r < 4; ++r) {
        int row = bm * 128 + wr * 64 + mt * 16 + fq * 4 + r;
        int col = bn * 128 + wc * 64 + nt * 16 + fr;
        float val = acc[mt][nt][r];
        if (OUT_BF16)
          reinterpret_cast<unsigned short*>(Cv)[(size_t)row * Nd + col] = f2b(val);
        else
          reinterpret_cast<float*>(Cv)[(size_t)row * Nd + col] = val;
      }
}

// ---------------- V transpose: qkv -> Vt[b*16+h][d][s] ----------------
__global__ __launch_bounds__(256) void vtrans(const unsigned short* __restrict__ qkv,
                                              unsigned short* __restrict__ vt) {
  __shared__ unsigned short Ts[64][72];
  int t = threadIdx.x;
  int kb = blockIdx.x;
  int bh = blockIdx.y;
  int b = bh >> 4, h = bh & 15;
  int k0 = kb * 64;
#pragma unroll
  for (int i = 0; i < 2; ++i) {
    int c = t + i * 256;
    int r = c >> 3, q = c & 7;
    int chunk = q ^ ((r >> 3) & 7);
    *reinterpret_cast<u16x8*>(&Ts[r][chunk * 8]) =
        *reinterpret_cast<const u16x8*>(
            qkv + ((size_t)(k0 + r) * BATCH + b) * N_QKV + h * 192 + 128 + q * 8);
  }
  __syncthreads();
#pragma unroll
  for (int i = 0; i < 2; ++i) {
    int c = t + i * 256;
    int d = c >> 3, q = c & 7;
    u16x8 o;
#pragma unroll
    for (int j = 0; j < 8; ++j) {
      int k = q * 8 + j;
      int chunk = (d >> 3) ^ q;
      o[j] = Ts[k][chunk * 8 + (d & 7)];
    }
    *reinterpret_cast<u16x8*>(&vt[((size_t)bh * 64 + d) * S_LEN + k0 + q * 8]) = o;
  }
}

// ---------------- flash attention: 2 q-tiles/wave ILP ----------------
// grid (S/128, B*H). Block covers 128 q-rows: chain A = q0+wid*16, chain B =
// +64. Two independent softmax/PV chains per wave hide dependency latency;
// K/Vt LDS reads shared between chains. Transport mapping = r8-verified.
__global__ __launch_bounds__(256) void attn_kernel(const unsigned short* __restrict__ qkv,
                                                   const unsigned short* __restrict__ vt,
                                                   unsigned short* __restrict__ att) {
  __shared__ unsigned short Ks[2][64][72];   // [k][d], dbuf
  __shared__ unsigned short VtS[2][64][72];  // [d][k], dbuf
  int t = threadIdx.x;
  int wid = t >> 6, lane = t & 63;
  int fr = lane & 15, fq = lane >> 4;
  int bh = blockIdx.y;
  int b = bh >> 4;
  int h = bh & 15;
  int q0 = blockIdx.x * 128;

  int srow = t >> 3, sc8 = (t & 7) * 8;

  // Q fragments, chains A and B (B operand): lane holds q-row fr
  int qiA = q0 + wid * 16 + fr;
  const unsigned short* qrowA = qkv + ((size_t)qiA * BATCH + b) * N_QKV + h * 192;
  const unsigned short* qrowB = qrowA + (size_t)64 * BATCH * N_QKV;
  bf16x8 qfA0 = *reinterpret_cast<const bf16x8*>(qrowA + fq * 8);
  bf16x8 qfA1 = *reinterpret_cast<const bf16x8*>(qrowA + 32 + fq * 8);
  bf16x8 qfB0 = *reinterpret_cast<const bf16x8*>(qrowB + fq * 8);
  bf16x8 qfB1 = *reinterpret_cast<const bf16x8*>(qrowB + 32 + fq * 8);
#pragma unroll
  for (int j = 0; j < 8; ++j) {
    qfA0[j] = (short)f2b_fast(0.125f * b2f((unsigned short)qfA0[j]));
    qfA1[j] = (short)f2b_fast(0.125f * b2f((unsigned short)qfA1[j]));
    qfB0[j] = (short)f2b_fast(0.125f * b2f((unsigned short)qfB0[j]));
    qfB1[j] = (short)f2b_fast(0.125f * b2f((unsigned short)qfB1[j]));
  }

  f32x4 oA[4], oB[4];
#pragma unroll
  for (int dt = 0; dt < 4; ++dt) {
    oA[dt] = (f32x4){0.f, 0.f, 0.f, 0.f};
    oB[dt] = (f32x4){0.f, 0.f, 0.f, 0.f};
  }
  float mA = -1e30f, lA = 0.f, mB = -1e30f, lB = 0.f;

  // shuffle source lanes (r8-verified mapping)
  int sl0 = fr + ((fq & 1) << 5);
  int sl1 = sl0 + 16;
  int hi = (fq >> 1) & 1;

  // prologue: stage tile 0 into buf 0
#pragma unroll
  for (int i = 0; i < 2; ++i) {
    int row = srow + i * 32;
    *reinterpret_cast<u16x8*>(&Ks[0][row][sc8]) = *reinterpret_cast<const u16x8*>(
        qkv + ((size_t)row * BATCH + b) * N_QKV + h * 192 + 64 + sc8);
    *reinterpret_cast<u16x8*>(&VtS[0][row][sc8]) = *reinterpret_cast<const u16x8*>(
        vt + ((size_t)bh * 64 + row) * S_LEN + sc8);
  }
  __syncthreads();

  for (int kt = 0; kt < S_LEN / 64; ++kt) {
    int cur = kt & 1, nxt = cur ^ 1;

    // T14: next tile's global loads issued early
    u16x8 kreg[2], vreg[2];
    if (kt + 1 < S_LEN / 64) {
#pragma unroll
      for (int i = 0; i < 2; ++i) {
        int row = srow + i * 32;
        kreg[i] = *reinterpret_cast<const u16x8*>(
            qkv + ((size_t)((kt + 1) * 64 + row) * BATCH + b) * N_QKV + h * 192 + 64 + sc8);
        vreg[i] = *reinterpret_cast<const u16x8*>(
            vt + ((size_t)bh * 64 + row) * S_LEN + (kt + 1) * 64 + sc8);
      }
    }

    // S^T = K * Q^T for both chains; K fragments loaded once, used twice
    f32x4 sA[4], sB[4];
#pragma unroll
    for (int nt = 0; nt < 4; ++nt) {
      bf16x8 bk0 = *reinterpret_cast<const bf16x8*>(&Ks[cur][nt * 16 + fr][fq * 8]);
      bf16x8 bk1 = *reinterpret_cast<const bf16x8*>(&Ks[cur][nt * 16 + fr][32 + fq * 8]);
      f32x4 x = (f32x4){0.f, 0.f, 0.f, 0.f};
      x = __builtin_amdgcn_mfma_f32_16x16x32_bf16(bk0, qfA0, x, 0, 0, 0);
      x = __builtin_amdgcn_mfma_f32_16x16x32_bf16(bk1, qfA1, x, 0, 0, 0);
      sA[nt] = x;
      f32x4 y = (f32x4){0.f, 0.f, 0.f, 0.f};
      y = __builtin_amdgcn_mfma_f32_16x16x32_bf16(bk0, qfB0, y, 0, 0, 0);
      y = __builtin_amdgcn_mfma_f32_16x16x32_bf16(bk1, qfB1, y, 0, 0, 0);
      sB[nt] = y;
    }

    // row max, chain A (max3-fusable)
    float ma = fmaxf(fmaxf(sA[0][0], sA[0][1]), sA[0][2]);
    ma = fmaxf(fmaxf(ma, sA[0][3]), sA[1][0]);
    ma = fmaxf(fmaxf(ma, sA[1][1]), sA[1][2]);
    float mc = fmaxf(fmaxf(sA[2][0], sA[2][1]), sA[2][2]);
    mc = fmaxf(fmaxf(mc, sA[2][3]), sA[3][0]);
    mc = fmaxf(fmaxf(mc, sA[3][1]), sA[3][2]);
    float mxA = fmaxf(fmaxf(ma, sA[1][3]), fmaxf(mc, sA[3][3]));
    mxA = fmaxf(mxA, __shfl_xor(mxA, 16));
    mxA = fmaxf(mxA, __shfl_xor(mxA, 32));
    // chain B
    float mb = fmaxf(fmaxf(sB[0][0], sB[0][1]), sB[0][2]);
    mb = fmaxf(fmaxf(mb, sB[0][3]), sB[1][0]);
    mb = fmaxf(fmaxf(mb, sB[1][1]), sB[1][2]);
    float md = fmaxf(fmaxf(sB[2][0], sB[2][1]), sB[2][2]);
    md = fmaxf(fmaxf(md, sB[2][3]), sB[3][0]);
    md = fmaxf(fmaxf(md, sB[3][1]), sB[3][2]);
    float mxB = fmaxf(fmaxf(mb, sB[1][3]), fmaxf(md, sB[3][3]));
    mxB = fmaxf(mxB, __shfl_xor(mxB, 16));
    mxB = fmaxf(mxB, __shfl_xor(mxB, 32));

    // T13 defer-max per chain (wave-uniform branches)
    if (!__all(mxA - mA <= 8.0f)) {
      float mnew = fmaxf(mA, mxA);
      float alpha = __expf(mA - mnew);
      mA = mnew; lA *= alpha;
#pragma unroll
      for (int dt = 0; dt < 4; ++dt) oA[dt] *= alpha;
    }
    if (!__all(mxB - mB <= 8.0f)) {
      float mnew = fmaxf(mB, mxB);
      float alpha = __expf(mB - mnew);
      mB = mnew; lB *= alpha;
#pragma unroll
      for (int dt = 0; dt < 4; ++dt) oB[dt] *= alpha;
    }

    // exp + sum, both chains
    float rsA = 0.f, rsB = 0.f;
#pragma unroll
    for (int nt = 0; nt < 4; ++nt)
#pragma unroll
      for (int r = 0; r < 4; ++r) {
        float pa = __expf(sA[nt][r] - mA);
        sA[nt][r] = pa; rsA += pa;
        float pb = __expf(sB[nt][r] - mB);
        sB[nt][r] = pb; rsB += pb;
      }
    rsA += __shfl_xor(rsA, 16); rsA += __shfl_xor(rsA, 32); lA += rsA;
    rsB += __shfl_xor(rsB, 16); rsB += __shfl_xor(rsB, 32); lB += rsB;

    // pack P via v_cvt_pk_bf16_f32
    unsigned pdA[8], pdB[8];
#pragma unroll
    for (int nt = 0; nt < 4; ++nt)
#pragma unroll
      for (int hh = 0; hh < 2; ++hh) {
        asm("v_cvt_pk_bf16_f32 %0, %1, %2"
            : "=v"(pdA[nt * 2 + hh]) : "v"(sA[nt][2 * hh]), "v"(sA[nt][2 * hh + 1]));
        asm("v_cvt_pk_bf16_f32 %0, %1, %2"
            : "=v"(pdB[nt * 2 + hh]) : "v"(sB[nt][2 * hh]), "v"(sB[nt][2 * hh + 1]));
      }

    // redistribute + PV; Vt fragments loaded once, used by both chains
#pragma unroll
    for (int kc = 0; kc < 2; ++kc) {
      int base = kc * 4;
      unsigned aA0 = (unsigned)__shfl((int)pdA[base + 0], sl0);
      unsigned aA1 = (unsigned)__shfl((int)pdA[base + 1], sl0);
      unsigned aA2 = (unsigned)__shfl((int)pdA[base + 2], sl0);
      unsigned aA3 = (unsigned)__shfl((int)pdA[base + 3], sl0);
      unsigned cA0 = (unsigned)__shfl((int)pdA[base + 0], sl1);
      unsigned cA1 = (unsigned)__shfl((int)pdA[base + 1], sl1);
      unsigned cA2 = (unsigned)__shfl((int)pdA[base + 2], sl1);
      unsigned cA3 = (unsigned)__shfl((int)pdA[base + 3], sl1);
      union { unsigned u[4]; bf16x8 v; } pbA;
      pbA.u[0] = hi ? aA2 : aA0;
      pbA.u[1] = hi ? aA3 : aA1;
      pbA.u[2] = hi ? cA2 : cA0;
      pbA.u[3] = hi ? cA3 : cA1;
      unsigned aB0 = (unsigned)__shfl((int)pdB[base + 0], sl0);
      unsigned aB1 = (unsigned)__shfl((int)pdB[base + 1], sl0);
      unsigned aB2 = (unsigned)__shfl((int)pdB[base + 2], sl0);
      unsigned aB3 = (unsigned)__shfl((int)pdB[base + 3], sl0);
      unsigned cB0 = (unsigned)__shfl((int)pdB[base + 0], sl1);
      unsigned cB1 = (unsigned)__shfl((int)pdB[base + 1], sl1);
      unsigned cB2 = (unsigned)__shfl((int)pdB[base + 2], sl1);
      unsigned cB3 = (unsigned)__shfl((int)pdB[base + 3], sl1);
      union { unsigned u[4]; bf16x8 v; } pbB;
      pbB.u[0] = hi ? aB2 : aB0;
      pbB.u[1] = hi ? aB3 : aB1;
      pbB.u[2] = hi ? cB2 : cB0;
      pbB.u[3] = hi ? cB3 : cB1;
#pragma unroll
      for (int dt = 0; dt < 4; ++dt) {
        bf16x8 vb = *reinterpret_cast<const bf16x8*>(&VtS[cur][dt * 16 + fr][kc * 32 + fq * 8]);
        oA[dt] = __builtin_amdgcn_mfma_f32_16x16x32_bf16(vb, pbA.v, oA[dt], 0, 0, 0);
        oB[dt] = __builtin_amdgcn_mfma_f32_16x16x32_bf16(vb, pbB.v, oB[dt], 0, 0, 0);
      }
    }

    // write next tile to the other buffer
    if (kt + 1 < S_LEN / 64) {
#pragma unroll
      for (int i = 0; i < 2; ++i) {
        int row = srow + i * 32;
        *reinterpret_cast<u16x8*>(&Ks[nxt][row][sc8]) = kreg[i];
        *reinterpret_cast<u16x8*>(&VtS[nxt][row][sc8]) = vreg[i];
      }
    }
    __syncthreads();   // single barrier per tile
  }

  // epilogue: both chains; lane layout q=fr, d = dt*16+fq*4+r
  float invlA = 1.0f / lA, invlB = 1.0f / lB;
  int qA = q0 + wid * 16 + fr;
#pragma unroll
  for (int dt = 0; dt < 4; ++dt) {
    u16x4 ovA, ovB;
#pragma unroll
    for (int r = 0; r < 4; ++r) {
      ovA[r] = f2b(oA[dt][r] * invlA);
      ovB[r] = f2b(oB[dt][r] * invlB);
    }
    int d = dt * 16 + fq * 4;
    *reinterpret_cast<u16x4*>(&att[((size_t)qA * BATCH + b) * EMB + h * 64 + d]) = ovA;
    *reinterpret_cast<u16x4*>(&att[((size_t)(qA + 64) * BATCH + b) * EMB + h * 64 + d]) = ovB;
  }
}

extern "C" void kernel_launch(void* const* d_in, const int* in_sizes, int n_in,
                              void* d_out, int out_size, void* d_ws, size_t ws_size,
                              hipStream_t stream) {
  const float* q_in  = (const float*)d_in[0];
  const float* w_in  = (const float*)d_in[3];
  const float* w_out = (const float*)d_in[4];
  float* out = (float*)d_out;

  unsigned short* ws  = (unsigned short*)d_ws;
  unsigned short* Xb  = ws;                                  // 4096x1024 (dead after gemm1)
  unsigned short* Wb  = Xb + (size_t)M_ROWS * EMB;           // 3072x1024
  unsigned short* Ob  = Wb + (size_t)N_QKV * EMB;            // 1024x1024
  unsigned short* QKV = Ob + (size_t)EMB * EMB;              // 4096x3072
  unsigned short* ATT = QKV + (size_t)M_ROWS * N_QKV;        // 4096x1024
  unsigned short* Vt  = Xb;                                  // alias: 32*64*2048 == 4096*1024

  cvt_f32_bf16<<<(M_ROWS * EMB / 4 + 255) / 256, 256, 0, stream>>>(q_in, Xb, M_ROWS * EMB / 4);
  cvt_f32_bf16<<<(N_QKV * EMB / 4 + 255) / 256, 256, 0, stream>>>(w_in, Wb, N_QKV * EMB / 4);
  cvt_f32_bf16<<<(EMB * EMB / 4 + 255) / 256, 256, 0, stream>>>(w_out, Ob, EMB * EMB / 4);

  gemm_bt<1><<<dim3(N_QKV / 128, M_ROWS / 128), 256, 0, stream>>>(Xb, Wb, QKV, M_ROWS, N_QKV, EMB);
  vtrans<<<dim3(S_LEN / 64, BATCH * NH), 256, 0, stream>>>(QKV, Vt);
  attn_kernel<<<dim3(S_LEN / 128, BATCH * NH), 256, 0, stream>>>(QKV, Vt, ATT);
  gemm_bt<0><<<dim3(EMB / 128, M_ROWS / 128), 256, 0, stream>>>(ATT, Ob, out, M_ROWS, EMB, EMB);
}